// Round 8
// baseline (191.819 us; speedup 1.0000x reference)
//
#include <hip/hip_runtime.h>
#include <math.h>

constexpr int NB = 8, NC = 64, NO = 64, NH = 64, NW = 64;

using f32x4 = __attribute__((ext_vector_type(4))) float;
using s16x8 = __attribute__((ext_vector_type(8))) short;
using u32x4 = __attribute__((ext_vector_type(4))) unsigned int;

// packed f32x2 -> bf16x2 (RNE). No builtin on gfx950 — inline asm per guide T12.
__device__ __forceinline__ unsigned int pk2(float lo, float hi) {
    unsigned int r;
    asm("v_cvt_pk_bf16_f32 %0, %1, %2" : "=v"(r) : "v"(lo), "v"(hi));
    return r;   // lo in bits[15:0], hi in bits[31:16]
}
__device__ __forceinline__ unsigned short f2bf(float f) {
    unsigned u = __builtin_bit_cast(unsigned, f);
    return (unsigned short)((u + 0x7fffu + ((u >> 16) & 1u)) >> 16);
}
__device__ __forceinline__ float bf2f(unsigned short s) {
    unsigned u = ((unsigned)s) << 16;
    return __builtin_bit_cast(float, u);
}

// Grid 512 = b(8) x hpair(32) x osub(2). Block 512 thr = 8 waves.
// Block tile: 2 h-rows x 64 w x 32 o (obase = osub*32).
// Wave wv: ofrag = wv&1 (16 o), ltile = wv>>1 -> hrow = ltile>>1, whalf = ltile&1; 2 n-tiles.
// MFMA A = W (rows=o), B = x (cols=w). D: row(o)=q*4+reg, col(w)=c0 -> coalesced stores.
// waves_per_eu(4,4): pin allocator at 128 VGPRs (R7 regression: it chose 64 -> 600 MB spill).
__global__ __launch_bounds__(512, 4) __attribute__((amdgpu_waves_per_eu(4, 4)))
void acda_kernel(const float* __restrict__ x, const float* __restrict__ w_gen,
                 const float* __restrict__ b_gen, const float* __restrict__ pos_enc,
                 float* __restrict__ out)
{
    __shared__ __align__(16) unsigned char arena[38016];      // Xs (16KB) then Patch bf16 [4][66][36]
    __shared__ __align__(16) unsigned short Wb[2][4][32 * 64]; // 32 KB: dbuf x 4 atoms [o_l][c] swz
    __shared__ float BiasL[36 * 32];                           // 4.6 KB [k*4+a][o_l]

    unsigned short* Patch = reinterpret_cast<unsigned short*>(arena);

    const int tid = threadIdx.x, lane = tid & 63, wv = tid >> 6;
    const int c0 = lane & 15, q = lane >> 4;
    const int ofrag = wv & 1, ltile = wv >> 1;
    const int hrow = ltile >> 1, whalf = ltile & 1;

    const int bx = blockIdx.x;
    const int osub = bx & 1;
    const int hp   = (bx >> 1) & 31;
    const int b    = bx >> 6;
    const int hbase = hp * 2, obase = osub * 32;
    const size_t xB = (size_t)b * NC * NH * NW;

    // ---- stage Xs: x[b,c,hbase+hs,w] -> arena[loc=hs*64+w][c] bf16 swizzled ----
    {
        const int w = lane, oct = wv;
#pragma unroll
        for (int hs = 0; hs < 2; ++hs) {
            const float* src = x + xB + (size_t)(oct * 8) * (NH * NW) + (hbase + hs) * NW + w;
            u32x4 pkv;
#pragma unroll
            for (int i = 0; i < 4; ++i)
                pkv[i] = pk2(src[(2 * i) * (NH * NW)], src[(2 * i + 1) * (NH * NW)]);
            const int loc = hs * 64 + w;
            const int byte = loc * 128 + ((oct * 16) ^ ((loc & 7) << 4));
            *reinterpret_cast<u32x4*>(arena + byte) = pkv;
        }
    }
    __syncthreads();
    // ---- x fragments -> regs ----
    s16x8 xf[2][2];
#pragma unroll
    for (int nt = 0; nt < 2; ++nt) {
        const int loc = hrow * 64 + whalf * 32 + nt * 16 + c0;
#pragma unroll
        for (int kh2 = 0; kh2 < 2; ++kh2) {
            const int byte = loc * 128 + ((kh2 * 64 + q * 16) ^ ((loc & 7) << 4));
            xf[nt][kh2] = *reinterpret_cast<s16x8*>(arena + byte);
        }
    }
    __syncthreads();   // Xs reads done; arena becomes Patch

    // ---- W stage helpers (a = tid>>7, o_l = (tid>>2)&31, j4 = tid&3 -> 16 floats) ----
    const int sa = tid >> 7, so = (tid >> 2) & 31, sj = tid & 3;
    const float* wsrc0 = w_gen + (size_t)(((obase + so) * 4 + sa) * 9) * NC + sj * 16;
    const int wb0 = sa * 4096 + so * 128 + (((sj * 2) * 16) ^ ((so & 7) << 4));
    const int wb1 = sa * 4096 + so * 128 + (((sj * 2 + 1) * 16) ^ ((so & 7) << 4));

    float4 wl[4];
    auto loadW = [&](int k) {   // issue 4 global dwordx4 for tap k
        const float4* p = reinterpret_cast<const float4*>(wsrc0 + (size_t)k * NC);
        wl[0] = p[0]; wl[1] = p[1]; wl[2] = p[2]; wl[3] = p[3];
    };
    auto writeW = [&](int nbuf) {   // cvt + 2 ds_write_b128
        u32x4 v0, v1;
#pragma unroll
        for (int i = 0; i < 2; ++i) {
            v0[2 * i]     = pk2(wl[i].x, wl[i].y);
            v0[2 * i + 1] = pk2(wl[i].z, wl[i].w);
            v1[2 * i]     = pk2(wl[2 + i].x, wl[2 + i].y);
            v1[2 * i + 1] = pk2(wl[2 + i].z, wl[2 + i].w);
        }
        unsigned char* base = reinterpret_cast<unsigned char*>(&Wb[nbuf][0][0]);
        *reinterpret_cast<u32x4*>(base + wb0) = v0;
        *reinterpret_cast<u32x4*>(base + wb1) = v1;
    };

    loadW(0);   // k=0 loads in flight

    // ---- stage Patch bf16: x[b,obase+o_l,hbase-1+hhi,ww] -> Patch[hhi][ww+1][o_l] ----
    {
        const int o_l = tid >> 4, i4 = (tid & 15) * 4;
        const float* xo = x + xB + (size_t)(obase + o_l) * (NH * NW);
#pragma unroll
        for (int hhi = 0; hhi < 4; ++hhi) {
            const int hh = hbase - 1 + hhi;
            float4 v = {0.f, 0.f, 0.f, 0.f};
            if (hh >= 0 && hh < NH) v = *reinterpret_cast<const float4*>(xo + hh * NW + i4);
            unsigned short* p = Patch + (hhi * 66 + i4 + 1) * 36 + o_l;
            p[0] = f2bf(v.x); p[36] = f2bf(v.y); p[72] = f2bf(v.z); p[108] = f2bf(v.w);
        }
        if (tid < 256) {   // halo columns wwi = 0, 65
            const int hhi = tid >> 6, side = (tid >> 5) & 1, ol2 = tid & 31;
            Patch[(hhi * 66 + (side ? 65 : 0)) * 36 + ol2] = 0;
        }
    }
    // ---- bias: BiasL[(k*4+a)*32 + o_l] ----
    for (int i = tid; i < 1152; i += 512) {
        const int k = i >> 7, a = (i >> 5) & 3, o_l = i & 31;
        BiasL[i] = b_gen[((obase + o_l) * 4 + a) * 9 + k];
    }
    // ---- attention attv[a][nt] ----
    float pe[8];
#pragma unroll
    for (int i = 0; i < 8; ++i) pe[i] = pos_enc[i];
    const float gy = -1.0f + (2.0f / 63.0f) * (float)(hbase + hrow);
    float attv[4][2];
#pragma unroll
    for (int a = 0; a < 4; ++a)
#pragma unroll
        for (int nt = 0; nt < 2; ++nt) {
            const float gx = -1.0f + (2.0f / 63.0f) * (float)(whalf * 32 + nt * 16 + c0);
            const float dx = gx - pe[2 * a], dy = gy - pe[2 * a + 1];
            attv[a][nt] = __expf(-(dx * dx + dy * dy));
        }

    writeW(0);
    __syncthreads();   // Wb[0], Patch, BiasL ready

    const int o4 = ofrag * 16 + q * 4;
    const int wrow = ofrag * 16 + c0;
    const int swz = (wrow & 7) << 4;
    // Patch byte: element ((hrow+kh)*66 + w_local + kw)*36 + o4, *2 bytes
    const int pb0 = ((hrow * 66 + whalf * 32 + c0) * 36 + o4) * 2;

    float outacc[2][4] = {};

#pragma unroll
    for (int k = 0; k < 9; ++k) {
        const int buf = k & 1;
        if (k < 8) loadW(k + 1);           // issue-early (T14)
        float tsum[2][4] = {};
#pragma unroll
        for (int a = 0; a < 4; ++a) {
            const unsigned char* Wt = reinterpret_cast<const unsigned char*>(&Wb[buf][a][0]);
            const s16x8 wf0 = *reinterpret_cast<const s16x8*>(Wt + wrow * 128 + ((q * 16) ^ swz));
            const s16x8 wf1 = *reinterpret_cast<const s16x8*>(Wt + wrow * 128 + ((64 + q * 16) ^ swz));
            const f32x4 bb = *reinterpret_cast<const f32x4*>(BiasL + (k * 4 + a) * 32 + o4);
#pragma unroll
            for (int nt = 0; nt < 2; ++nt) {
                f32x4 acc = bb;
                acc = __builtin_amdgcn_mfma_f32_16x16x32_bf16(wf0, xf[nt][0], acc, 0, 0, 0);
                acc = __builtin_amdgcn_mfma_f32_16x16x32_bf16(wf1, xf[nt][1], acc, 0, 0, 0);
                const float at = attv[a][nt];
#pragma unroll
                for (int r = 0; r < 4; ++r)
                    tsum[nt][r] = fmaf(at, fmaxf(acc[r], 0.f), tsum[nt][r]);
            }
        }
        const int kh = k / 3, kw = k - 3 * kh;
#pragma unroll
        for (int nt = 0; nt < 2; ++nt) {
            const ushort4 pu = *reinterpret_cast<const ushort4*>(
                reinterpret_cast<const unsigned char*>(Patch) + pb0 + (kh * 66 + nt * 16 + kw) * 72);
            outacc[nt][0] = fmaf(tsum[nt][0], bf2f(pu.x), outacc[nt][0]);
            outacc[nt][1] = fmaf(tsum[nt][1], bf2f(pu.y), outacc[nt][1]);
            outacc[nt][2] = fmaf(tsum[nt][2], bf2f(pu.z), outacc[nt][2]);
            outacc[nt][3] = fmaf(tsum[nt][3], bf2f(pu.w), outacc[nt][3]);
        }
        if (k < 8) writeW(buf ^ 1);        // write-late (T14)
        __syncthreads();
    }

    // ---- coalesced stores ----
    const int h = hbase + hrow;
#pragma unroll
    for (int nt = 0; nt < 2; ++nt) {
        const int wcol = whalf * 32 + nt * 16 + c0;
#pragma unroll
        for (int r = 0; r < 4; ++r) {
            const int o = obase + o4 + r;
            out[(((size_t)b * NO + o) * NH + h) * NW + wcol] = outacc[nt][r];
        }
    }
}

extern "C" void kernel_launch(void* const* d_in, const int* in_sizes, int n_in,
                              void* d_out, int out_size, void* d_ws, size_t ws_size,
                              hipStream_t stream) {
    const float* x       = (const float*)d_in[0];
    const float* w_gen   = (const float*)d_in[1];
    const float* b_gen   = (const float*)d_in[2];
    const float* pos_enc = (const float*)d_in[3];
    float* out = (float*)d_out;

    dim3 grid(NB * 32 * 2);   // 512 workgroups
    dim3 block(512);
    hipLaunchKernelGGL(acda_kernel, grid, block, 0, stream,
                       x, w_gen, b_gen, pos_enc, out);
}

// Round 9
// 27.856 us; speedup vs baseline: 6.8860x; 6.8860x over previous
//
#include <hip/hip_runtime.h>
#include <math.h>

constexpr int NB = 8, NC = 64, NO = 64, NH = 64, NW = 64, NA = 4, NKK = 9;

using f32x4 = __attribute__((ext_vector_type(4))) float;
using s16x8 = __attribute__((ext_vector_type(8))) short;
using u32x4 = __attribute__((ext_vector_type(4))) unsigned int;

// packed f32x2 -> bf16x2 (RNE), v_cvt_pk_bf16_f32 (no builtin on gfx950)
__device__ __forceinline__ unsigned int pk2(float lo, float hi) {
    unsigned int r;
    asm("v_cvt_pk_bf16_f32 %0, %1, %2" : "=v"(r) : "v"(lo), "v"(hi));
    return r;   // lo in bits[15:0], hi in bits[31:16]
}
__device__ __forceinline__ unsigned short f2bf(float f) {
    unsigned u = __builtin_bit_cast(unsigned, f);
    return (unsigned short)((u + 0x7fffu + ((u >> 16) & 1u)) >> 16);
}
__device__ __forceinline__ float bf2f(unsigned short s) {
    unsigned u = ((unsigned)s) << 16;
    return __builtin_bit_cast(float, u);
}

// Grid 512 = b(8) x hpair(32) x osub(2). Block 512 thr = 8 waves.  [R4-verified structure]
// Block tile: 2 h-rows x 64 w x 32 o (obase = osub*32).
// Wave wv: ofrag = wv&1 (16 o), ltile = wv>>1 -> hrow = ltile>>1, whalf = ltile&1; 2 n-tiles.
// MFMA A = W (rows=o), B = x (cols=w). D: row(o)=q*4+reg, col(w)=c0 -> coalesced stores.
__global__ __launch_bounds__(512, 4)
void acda_kernel(const float* __restrict__ x, const float* __restrict__ w_gen,
                 const float* __restrict__ b_gen, const float* __restrict__ pos_enc,
                 float* __restrict__ out)
{
    __shared__ unsigned short Xs[128 * 64];          // 16 KB [loc][c] bf16, XOR-swizzled
    __shared__ unsigned short Wb[2][2][32 * 64];     // 16 KB dbuf x 2taps [o_l][c] bf16, swizzled
    __shared__ unsigned short Patch[4 * 66 * 36];    // 19 KB [hhi][wwi][o_l(32)+pad4] bf16
    __shared__ float BiasL[36 * 32];                 // 4.6 KB [tap][o_l]

    const int tid  = threadIdx.x;
    const int lane = tid & 63;
    const int wv   = tid >> 6;
    const int c0   = lane & 15, q = lane >> 4;
    const int ofrag = wv & 1;
    const int ltile = wv >> 1;
    const int hrow = ltile >> 1, whalf = ltile & 1;

    const int bx    = blockIdx.x;
    const int osub  = bx & 1;
    const int hp    = (bx >> 1) & 31;
    const int b     = bx >> 6;
    const int hbase = hp * 2;
    const int obase = osub * 32;

    const size_t xB = (size_t)b * NC * NH * NW;

    // ---- stage Xs: x[b, c, hbase+hs, w] -> Xs[loc = hs*64+w][c] (bf16, swizzled) ----
    {
        const int w = lane, oct = wv;
        for (int hs = 0; hs < 2; ++hs) {
            const float* src = x + xB + (size_t)(oct * 8) * (NH * NW) + (hbase + hs) * NW + w;
            u32x4 pkv;
#pragma unroll
            for (int i = 0; i < 4; ++i)
                pkv[i] = pk2(src[(size_t)(2 * i) * (NH * NW)], src[(size_t)(2 * i + 1) * (NH * NW)]);
            const int loc  = hs * 64 + w;
            const int byte = loc * 128 + ((oct * 16) ^ ((loc & 7) << 4));
            *reinterpret_cast<u32x4*>(reinterpret_cast<char*>(Xs) + byte) = pkv;
        }
    }
    // ---- stage Patch: x[b, obase+o_l, hbase-1+hhi, ww] -> Patch[hhi][ww+1][o_l], bf16 ----
    {
        const int o_l = tid >> 4, i4 = (tid & 15) * 4;
        const float* xo = x + xB + (size_t)(obase + o_l) * (NH * NW);
#pragma unroll
        for (int hhi = 0; hhi < 4; ++hhi) {
            const int hh = hbase - 1 + hhi;
            float4 v = {0.f, 0.f, 0.f, 0.f};
            if (hh >= 0 && hh < NH) v = *reinterpret_cast<const float4*>(xo + hh * NW + i4);
            unsigned short* p = Patch + (hhi * 66 + i4 + 1) * 36 + o_l;
            p[0 * 36] = f2bf(v.x); p[1 * 36] = f2bf(v.y);
            p[2 * 36] = f2bf(v.z); p[3 * 36] = f2bf(v.w);
        }
        if (tid < 256) {   // zero w-halo columns (wwi = 0 and 65)
            const int hhi = tid >> 6, side = (tid >> 5) & 1, ol2 = tid & 31;
            Patch[(hhi * 66 + (side ? 65 : 0)) * 36 + ol2] = 0;
        }
    }
    // ---- stage bias: BiasL[tap][o_l] = b_gen[(obase+o_l)*36 + tap] ----
    for (int idx = tid; idx < 36 * 32; idx += 512) {
        const int t = idx >> 5, o_l = idx & 31;
        BiasL[t * 32 + o_l] = b_gen[(obase + o_l) * 36 + t];
    }
    // ---- W stage: 2 taps (tap0, tap0+1) into Wb[buf][0/1], 16B/thread ----
    auto stageW2 = [&](int tap0, int buf) {
        const int half = tid >> 8;            // which tap
        const int tt   = tid & 255;
        const int o_l  = tt >> 3, cs = (tt & 7) * 8;
        const int f    = (obase + o_l) * 36 + tap0 + half;
        const float* src = w_gen + (size_t)f * NC + cs;
        float4 v0 = *reinterpret_cast<const float4*>(src);
        float4 v1 = *reinterpret_cast<const float4*>(src + 4);
        u32x4 pk;
        pk[0] = pk2(v0.x, v0.y); pk[1] = pk2(v0.z, v0.w);
        pk[2] = pk2(v1.x, v1.y); pk[3] = pk2(v1.z, v1.w);
        const int byte = o_l * 128 + ((cs * 2) ^ ((o_l & 7) << 4));
        *reinterpret_cast<u32x4*>(reinterpret_cast<char*>(Wb[buf][half]) + byte) = pk;
    };
    stageW2(0, 0);
    __syncthreads();

    // ---- x fragments -> registers (reused for all 36 taps) ----
    s16x8 xf[2][2];
#pragma unroll
    for (int nt = 0; nt < 2; ++nt) {
        const int loc = hrow * 64 + whalf * 32 + nt * 16 + c0;
#pragma unroll
        for (int kh2 = 0; kh2 < 2; ++kh2) {
            const int byte = loc * 128 + ((kh2 * 64 + q * 16) ^ ((loc & 7) << 4));
            xf[nt][kh2] = *reinterpret_cast<s16x8*>(reinterpret_cast<char*>(Xs) + byte);
        }
    }

    const int h = hbase + hrow;
    const float gy = -1.0f + (2.0f / 63.0f) * (float)h;
    float gxn[2];
#pragma unroll
    for (int nt = 0; nt < 2; ++nt)
        gxn[nt] = -1.0f + (2.0f / 63.0f) * (float)(whalf * 32 + nt * 16 + c0);

    float pe[8];
#pragma unroll
    for (int i = 0; i < 8; ++i) pe[i] = pos_enc[i];

    const int o4 = ofrag * 16 + q * 4;     // this lane's o_local row base
    const int wrow = ofrag * 16 + c0;      // A-frag row index in Wb
    // Patch byte offsets: element ((hrow+kh)*66 + (w_local+kw))*36 + o4, *2 bytes.
    int pbase[2];
#pragma unroll
    for (int nt = 0; nt < 2; ++nt)
        pbase[nt] = (hrow * 66 + whalf * 32 + nt * 16 + c0) * 72 + o4 * 2;

    float outacc[2][4] = {};
    float attn[2];
    int a = 0, k = 0, buf = 0;

    for (int it = 0; it < 18; ++it) {
        if (it < 17) stageW2(2 * it + 2, buf ^ 1);
#pragma unroll
        for (int half = 0; half < 2; ++half) {
            const int tap = 2 * it + half;
            if (k == 0) {
#pragma unroll
                for (int nt = 0; nt < 2; ++nt) {
                    const float dx = gxn[nt] - pe[2 * a], dy = gy - pe[2 * a + 1];
                    attn[nt] = __expf(-(dx * dx + dy * dy));
                }
            }
            const int kh = (k * 11) >> 5, kw = k - 3 * kh;
            const unsigned short* Wt = Wb[buf][half];
            const int sw = (wrow & 7) << 4;
            s16x8 wf0 = *reinterpret_cast<const s16x8*>(
                reinterpret_cast<const char*>(Wt) + wrow * 128 + ((q * 16) ^ sw));
            s16x8 wf1 = *reinterpret_cast<const s16x8*>(
                reinterpret_cast<const char*>(Wt) + wrow * 128 + ((64 + q * 16) ^ sw));
            const f32x4 bb = *reinterpret_cast<const f32x4*>(BiasL + tap * 32 + o4);
            const int pd = (kh * 66 + kw) * 72;
#pragma unroll
            for (int nt = 0; nt < 2; ++nt) {
                f32x4 acc = bb;
                acc = __builtin_amdgcn_mfma_f32_16x16x32_bf16(wf0, xf[nt][0], acc, 0, 0, 0);
                acc = __builtin_amdgcn_mfma_f32_16x16x32_bf16(wf1, xf[nt][1], acc, 0, 0, 0);
                const ushort4 pu = *reinterpret_cast<const ushort4*>(
                    reinterpret_cast<const char*>(Patch) + pbase[nt] + pd);
                const float at = attn[nt];
                outacc[nt][0] = fmaf(fmaxf(acc[0], 0.f) * at, bf2f(pu.x), outacc[nt][0]);
                outacc[nt][1] = fmaf(fmaxf(acc[1], 0.f) * at, bf2f(pu.y), outacc[nt][1]);
                outacc[nt][2] = fmaf(fmaxf(acc[2], 0.f) * at, bf2f(pu.z), outacc[nt][2]);
                outacc[nt][3] = fmaf(fmaxf(acc[3], 0.f) * at, bf2f(pu.w), outacc[nt][3]);
            }
            if (++k == 9) { k = 0; ++a; }
        }
        __syncthreads();
        buf ^= 1;
    }

    // ---- coalesced stores: col = w (lane&15) contiguous ----
#pragma unroll
    for (int nt = 0; nt < 2; ++nt) {
        const int wcol = whalf * 32 + nt * 16 + c0;
#pragma unroll
        for (int r = 0; r < 4; ++r) {
            const int o = obase + o4 + r;
            out[(((size_t)b * NO + o) * NH + h) * NW + wcol] = outacc[nt][r];
        }
    }
}

extern "C" void kernel_launch(void* const* d_in, const int* in_sizes, int n_in,
                              void* d_out, int out_size, void* d_ws, size_t ws_size,
                              hipStream_t stream) {
    const float* x       = (const float*)d_in[0];
    const float* w_gen   = (const float*)d_in[1];
    const float* b_gen   = (const float*)d_in[2];
    const float* pos_enc = (const float*)d_in[3];
    float* out = (float*)d_out;

    dim3 grid(NB * 32 * 2);   // 512 workgroups
    dim3 block(512);
    hipLaunchKernelGGL(acda_kernel, grid, block, 0, stream,
                       x, w_gen, b_gen, pos_enc, out);
}

// Round 10
// 26.899 us; speedup vs baseline: 7.1311x; 1.0356x over previous
//
#include <hip/hip_runtime.h>
#include <math.h>

constexpr int NB = 8, NC = 64, NO = 64, NH = 64, NW = 64, NA = 4, NKK = 9;

using f32x4 = __attribute__((ext_vector_type(4))) float;
using s16x8 = __attribute__((ext_vector_type(8))) short;
using u32x4 = __attribute__((ext_vector_type(4))) unsigned int;

// packed f32x2 -> bf16x2 (RNE), v_cvt_pk_bf16_f32 (no builtin on gfx950)
__device__ __forceinline__ unsigned int pk2(float lo, float hi) {
    unsigned int r;
    asm("v_cvt_pk_bf16_f32 %0, %1, %2" : "=v"(r) : "v"(lo), "v"(hi));
    return r;   // lo in bits[15:0], hi in bits[31:16]
}
__device__ __forceinline__ unsigned short f2bf(float f) {
    unsigned u = __builtin_bit_cast(unsigned, f);
    return (unsigned short)((u + 0x7fffu + ((u >> 16) & 1u)) >> 16);
}
__device__ __forceinline__ float bf2f(unsigned short s) {
    unsigned u = ((unsigned)s) << 16;
    return __builtin_bit_cast(float, u);
}

// Grid 512 = b(8) x hpair(32) x osub(2). Block 512 thr = 8 waves.  [R4/R9-verified structure]
// Block tile: 2 h-rows x 64 w x 32 o (obase = osub*32).
// Wave wv: ofrag = wv&1 (16 o), ltile = wv>>1 -> hrow = ltile>>1, whalf = ltile&1; 2 n-tiles.
// MFMA A = W (rows=o), B = x (cols=w). D: row(o)=q*4+reg, col(w)=c0 -> coalesced stores.
// NOTE launch_bounds 2nd arg is CUDA-style min BLOCKS/CU (measured R7/R8: (512,4)->64 VGPR
// -> 600MB spill; (512,2)->128 VGPR). LDS 55.6KB caps at 2 blocks/CU anyway.
__global__ __launch_bounds__(512, 2)
void acda_kernel(const float* __restrict__ x, const float* __restrict__ w_gen,
                 const float* __restrict__ b_gen, const float* __restrict__ pos_enc,
                 float* __restrict__ out)
{
    __shared__ unsigned short Xs[128 * 64];          // 16 KB [loc][c] bf16, XOR-swizzled
    __shared__ unsigned short Wb[2][2][32 * 64];     // 16 KB dbuf x 2taps [o_l][c] bf16, swizzled
    __shared__ unsigned short Patch[4 * 66 * 36];    // 19 KB [hhi][wwi][o_l(32)+pad4] bf16
    __shared__ float BiasL[36 * 32];                 // 4.6 KB [tap][o_l]

    const int tid  = threadIdx.x;
    const int lane = tid & 63;
    const int wv   = tid >> 6;
    const int c0   = lane & 15, q = lane >> 4;
    const int ofrag = wv & 1;
    const int ltile = wv >> 1;
    const int hrow = ltile >> 1, whalf = ltile & 1;

    const int bx    = blockIdx.x;
    const int osub  = bx & 1;
    const int hp    = (bx >> 1) & 31;
    const int b     = bx >> 6;
    const int hbase = hp * 2;
    const int obase = osub * 32;

    const size_t xB = (size_t)b * NC * NH * NW;

    // ---- W staging, T14-split: loadW2 (global->reg) early, writeW2 (cvt+ds_write) late ----
    const int sW_half = tid >> 8;                  // which tap of the pair
    const int sW_ol   = (tid & 255) >> 3;
    const int sW_cs   = (tid & 7) * 8;
    const float* sW_src0 = w_gen + (size_t)((obase + sW_ol) * 36 + sW_half) * NC + sW_cs;
    const int sW_byte = sW_ol * 128 + ((sW_cs * 2) ^ ((sW_ol & 7) << 4));

    float4 wr0, wr1;
    auto loadW2 = [&](int tap0) {
        const float* src = sW_src0 + (size_t)tap0 * NC;
        wr0 = *reinterpret_cast<const float4*>(src);
        wr1 = *reinterpret_cast<const float4*>(src + 4);
    };
    auto writeW2 = [&](int buf) {
        u32x4 pk;
        pk[0] = pk2(wr0.x, wr0.y); pk[1] = pk2(wr0.z, wr0.w);
        pk[2] = pk2(wr1.x, wr1.y); pk[3] = pk2(wr1.z, wr1.w);
        *reinterpret_cast<u32x4*>(reinterpret_cast<char*>(Wb[buf][sW_half]) + sW_byte) = pk;
    };

    loadW2(0);   // taps 0/1 loads in flight; Xs/Patch/bias staging below hides the latency

    // ---- stage Xs: x[b, c, hbase+hs, w] -> Xs[loc = hs*64+w][c] (bf16, swizzled) ----
    {
        const int w = lane, oct = wv;
        for (int hs = 0; hs < 2; ++hs) {
            const float* src = x + xB + (size_t)(oct * 8) * (NH * NW) + (hbase + hs) * NW + w;
            u32x4 pkv;
#pragma unroll
            for (int i = 0; i < 4; ++i)
                pkv[i] = pk2(src[(size_t)(2 * i) * (NH * NW)], src[(size_t)(2 * i + 1) * (NH * NW)]);
            const int loc  = hs * 64 + w;
            const int byte = loc * 128 + ((oct * 16) ^ ((loc & 7) << 4));
            *reinterpret_cast<u32x4*>(reinterpret_cast<char*>(Xs) + byte) = pkv;
        }
    }
    // ---- stage Patch: x[b, obase+o_l, hbase-1+hhi, ww] -> Patch[hhi][ww+1][o_l], bf16 ----
    {
        const int o_l = tid >> 4, i4 = (tid & 15) * 4;
        const float* xo = x + xB + (size_t)(obase + o_l) * (NH * NW);
#pragma unroll
        for (int hhi = 0; hhi < 4; ++hhi) {
            const int hh = hbase - 1 + hhi;
            float4 v = {0.f, 0.f, 0.f, 0.f};
            if (hh >= 0 && hh < NH) v = *reinterpret_cast<const float4*>(xo + hh * NW + i4);
            unsigned short* p = Patch + (hhi * 66 + i4 + 1) * 36 + o_l;
            p[0 * 36] = f2bf(v.x); p[1 * 36] = f2bf(v.y);
            p[2 * 36] = f2bf(v.z); p[3 * 36] = f2bf(v.w);
        }
        if (tid < 256) {   // zero w-halo columns (wwi = 0 and 65)
            const int hhi = tid >> 6, side = (tid >> 5) & 1, ol2 = tid & 31;
            Patch[(hhi * 66 + (side ? 65 : 0)) * 36 + ol2] = 0;
        }
    }
    // ---- stage bias: BiasL[tap][o_l] = b_gen[(obase+o_l)*36 + tap] ----
    for (int idx = tid; idx < 36 * 32; idx += 512) {
        const int t = idx >> 5, o_l = idx & 31;
        BiasL[t * 32 + o_l] = b_gen[(obase + o_l) * 36 + t];
    }
    writeW2(0);
    __syncthreads();

    // ---- x fragments -> registers (reused for all 36 taps) ----
    s16x8 xf[2][2];
#pragma unroll
    for (int nt = 0; nt < 2; ++nt) {
        const int loc = hrow * 64 + whalf * 32 + nt * 16 + c0;
#pragma unroll
        for (int kh2 = 0; kh2 < 2; ++kh2) {
            const int byte = loc * 128 + ((kh2 * 64 + q * 16) ^ ((loc & 7) << 4));
            xf[nt][kh2] = *reinterpret_cast<s16x8*>(reinterpret_cast<char*>(Xs) + byte);
        }
    }

    const int h = hbase + hrow;
    const float gy = -1.0f + (2.0f / 63.0f) * (float)h;
    float gxn[2];
#pragma unroll
    for (int nt = 0; nt < 2; ++nt)
        gxn[nt] = -1.0f + (2.0f / 63.0f) * (float)(whalf * 32 + nt * 16 + c0);

    float pe[8];
#pragma unroll
    for (int i = 0; i < 8; ++i) pe[i] = pos_enc[i];

    const int o4 = ofrag * 16 + q * 4;     // this lane's o_local row base
    const int wrow = ofrag * 16 + c0;      // A-frag row index in Wb
    // Patch byte offsets: element ((hrow+kh)*66 + (w_local+kw))*36 + o4, *2 bytes.
    int pbase[2];
#pragma unroll
    for (int nt = 0; nt < 2; ++nt)
        pbase[nt] = (hrow * 66 + whalf * 32 + nt * 16 + c0) * 72 + o4 * 2;

    float outacc[2][4] = {};
    float attn[2];
    int a = 0, k = 0, buf = 0;

    for (int it = 0; it < 18; ++it) {
        if (it < 17) loadW2(2 * it + 2);   // issue-early (T14)
#pragma unroll
        for (int half = 0; half < 2; ++half) {
            const int tap = 2 * it + half;
            if (k == 0) {
#pragma unroll
                for (int nt = 0; nt < 2; ++nt) {
                    const float dx = gxn[nt] - pe[2 * a], dy = gy - pe[2 * a + 1];
                    attn[nt] = __expf(-(dx * dx + dy * dy));
                }
            }
            const int kh = (k * 11) >> 5, kw = k - 3 * kh;
            const unsigned short* Wt = Wb[buf][half];
            const int sw = (wrow & 7) << 4;
            s16x8 wf0 = *reinterpret_cast<const s16x8*>(
                reinterpret_cast<const char*>(Wt) + wrow * 128 + ((q * 16) ^ sw));
            s16x8 wf1 = *reinterpret_cast<const s16x8*>(
                reinterpret_cast<const char*>(Wt) + wrow * 128 + ((64 + q * 16) ^ sw));
            const f32x4 bb = *reinterpret_cast<const f32x4*>(BiasL + tap * 32 + o4);
            const int pd = (kh * 66 + kw) * 72;
#pragma unroll
            for (int nt = 0; nt < 2; ++nt) {
                f32x4 acc = bb;
                acc = __builtin_amdgcn_mfma_f32_16x16x32_bf16(wf0, xf[nt][0], acc, 0, 0, 0);
                acc = __builtin_amdgcn_mfma_f32_16x16x32_bf16(wf1, xf[nt][1], acc, 0, 0, 0);
                const ushort4 pu = *reinterpret_cast<const ushort4*>(
                    reinterpret_cast<const char*>(Patch) + pbase[nt] + pd);
                const float at = attn[nt];
                outacc[nt][0] = fmaf(fmaxf(acc[0], 0.f) * at, bf2f(pu.x), outacc[nt][0]);
                outacc[nt][1] = fmaf(fmaxf(acc[1], 0.f) * at, bf2f(pu.y), outacc[nt][1]);
                outacc[nt][2] = fmaf(fmaxf(acc[2], 0.f) * at, bf2f(pu.z), outacc[nt][2]);
                outacc[nt][3] = fmaf(fmaxf(acc[3], 0.f) * at, bf2f(pu.w), outacc[nt][3]);
            }
            if (++k == 9) { k = 0; ++a; }
        }
        if (it < 17) writeW2(buf ^ 1);     // write-late (T14)
        __syncthreads();
        buf ^= 1;
    }

    // ---- coalesced stores: col = w (lane&15) contiguous ----
#pragma unroll
    for (int nt = 0; nt < 2; ++nt) {
        const int wcol = whalf * 32 + nt * 16 + c0;
#pragma unroll
        for (int r = 0; r < 4; ++r) {
            const int o = obase + o4 + r;
            out[(((size_t)b * NO + o) * NH + h) * NW + wcol] = outacc[nt][r];
        }
    }
}

extern "C" void kernel_launch(void* const* d_in, const int* in_sizes, int n_in,
                              void* d_out, int out_size, void* d_ws, size_t ws_size,
                              hipStream_t stream) {
    const float* x       = (const float*)d_in[0];
    const float* w_gen   = (const float*)d_in[1];
    const float* b_gen   = (const float*)d_in[2];
    const float* pos_enc = (const float*)d_in[3];
    float* out = (float*)d_out;

    dim3 grid(NB * 32 * 2);   // 512 workgroups
    dim3 block(512);
    hipLaunchKernelGGL(acda_kernel, grid, block, 0, stream,
                       x, w_gen, b_gen, pos_enc, out);
}